// Round 16
// baseline (96.553 us; speedup 1.0000x reference)
//
#include <hip/hip_runtime.h>

// LabelizerNet: avg-pool(6,2) -> RGB->HSV -> yellow/blue mask -> per-panel max/min
// Input : states (N, 3, 84, 84) f32   (N = 4096)
// Output: labels (N, 6) f32  [yellow panels 0..2, blue panels 0..2]
//
// Round 16: zero-overfetch AT 3 blocks/CU. Frames {24,20,20,20} rows; the 4-row
// inter-quarter overlap is kept via tiny LDS tail buffers (LDS->LDS copy of
// 252 f4/quarter) instead of a third full ring buffer (r15's occupancy killer).
// LDS = 53.1 KB -> 3 blocks/CU. Flat-chunk DMA staging: uniform 5 chunks/wave
// (6 for f0) -> clean counted vmcnt, never drained mid-stream. Blocks are
// persistent over IPB=2 images: f0(img+1) stages during q=3, so the pipeline
// never refills across images. Math bit-identical to all passing rounds.

#define CH_ELEMS 7056
#define CH_F4    1764              // 7056/4
#define IMG_F4   5292              // 3*7056/4
#define IPB      2

// LDS layout (float4 units)
#define BUF0 0                     // 1536 f4: f0 (slot 504 f4/ch) or f2 (slot 420)
#define BUF1 1536                  // 1280 f4: f1, f3 (slot 420 f4/ch)
#define TBA  2816                  // 252 f4: tail buffer A (4 rows x 21 f4 x 3ch)
#define TBB  3068                  // 252 f4: tail buffer B
#define LDS_TOT 3320               // 53120 B -> 3 blocks/CU

__device__ __forceinline__ void gl_lds16(const float4* g, float4* l) {
    __builtin_amdgcn_global_load_lds(
        (const __attribute__((address_space(1))) void*)(uintptr_t)(const void*)g,
        (__attribute__((address_space(3))) void*)(uintptr_t)(void*)l,
        16, 0, 0);
}

// Stage one frame: flat chunks of 64 f4; per-lane source crosses channel
// boundaries (allowed), LDS dest lane-linear (required). NPC = f4 per channel,
// MPW = chunks per wave, CLAMP = last valid flat index (src clamp; dest overrun
// lands in the buffer's allocated slack).
template<int NPC, int MPW, int CLAMP>
__device__ __forceinline__ void stageT(const float4* g0, float4* lb, int wid, int lane) {
    #pragma unroll
    for (int m = 0; m < MPW; ++m) {
        int i = (wid + 4 * m) * 64 + lane;
        int ii = min(i, CLAMP);
        int c = ii / NPC;
        gl_lds16(g0 + c * CH_F4 + (ii - c * NPC), lb + i);
    }
}

// Copy 4 rows (STARTROW..+3) of a main buffer (SLOTF4 f4/ch) into a tail buffer.
template<int SLOTF4, int STARTROW>
__device__ __forceinline__ void tailcopyT(const float4* mb, float4* tb, int tid) {
    if (tid < 252) {
        int c = tid / 84;
        int rem = tid - c * 84;
        tb[c * 84 + rem] = mb[c * SLOTF4 + STARTROW * 21 + rem];
    }
}

// Compute one quarter (24 input rows): rows r < RSPLIT from tail buf
// (c*336 + r*84 floats), rows r >= RSPLIT from main buf (c*MSLOTF + (r-RSPLIT)*84).
// Math verbatim from all passing rounds (bit-identical).
template<int RSPLIT, int MSLOTF>
__device__ __forceinline__ unsigned computeT(const float* tb, const float* mb, int tid) {
    unsigned my = 0u;
    if (tid < 200) {
        const int pr = tid / 20;             // pooled row within quarter
        const int xp = tid - pr * 20;        // pair-column 0..19
        const int x0 = 2 * xp, x1 = 2 * xp + 1;

        float t0[3], t1[3];
        #pragma unroll
        for (int c = 0; c < 3; ++c) {
            float P0[3], P1[3];
            #pragma unroll
            for (int j = 0; j < 3; ++j) {
                int r0 = 2 * pr + 2 * j;
                int r1 = r0 + 1;
                const float* row0 = (RSPLIT > 0 && r0 < RSPLIT)
                    ? (tb + c * 336 + r0 * 84)
                    : (mb + c * MSLOTF + (r0 - RSPLIT) * 84);
                const float* row1 = (RSPLIT > 0 && r1 < RSPLIT)
                    ? (tb + c * 336 + r1 * 84)
                    : (mb + c * MSLOTF + (r1 - RSPLIT) * 84);
                const float4* ra = (const float4*)(row0 + 4 * xp);
                const float4* rb = (const float4*)(row1 + 4 * xp);
                float4 qa0 = ra[0], qa1 = ra[1];
                float4 qb0 = rb[0], qb1 = rb[1];
                float a01 = qa0.x + qa0.y, a23 = qa0.z + qa0.w;
                float a45 = qa1.x + qa1.y, a67 = qa1.z + qa1.w;
                float rsa0 = (a01 + a23) + a45;      // rs[2j],  window x0
                float rsa1 = (a23 + a45) + a67;      // rs[2j],  window x1
                float b01 = qb0.x + qb0.y, b23 = qb0.z + qb0.w;
                float b45 = qb1.x + qb1.y, b67 = qb1.z + qb1.w;
                float rsb0 = (b01 + b23) + b45;      // rs[2j+1], window x0
                float rsb1 = (b23 + b45) + b67;      // rs[2j+1], window x1
                P0[j] = rsa0 + rsb0;                 // pair sum
                P1[j] = rsa1 + rsb1;
            }
            t0[c] = (P0[0] + P0[1]) + P0[2];         // == ((rs0+rs1)+(rs2+rs3))+(rs4+rs5)
            t1[c] = (P1[0] + P1[1]) + P1[2];
        }

        #pragma unroll
        for (int e = 0; e < 2; ++e) {
            float r = ((e == 0) ? t0[0] : t1[0]) / 36.0f;
            float g = ((e == 0) ? t0[1] : t1[1]) / 36.0f;
            float b = ((e == 0) ? t0[2] : t1[2]) / 36.0f;

            float maxc = fmaxf(r, fmaxf(g, b));
            float minc = fminf(r, fminf(g, b));
            float delta = maxc - minc;
            float s = (maxc == 0.0f) ? 0.0f : delta / maxc;
            float v = maxc;
            float h = 0.0f;
            if (delta != 0.0f) {
                float rc = (maxc - r) / delta;
                float gc = (maxc - g) / delta;
                float bc = (maxc - b) / delta;
                float hh = (r == maxc) ? (bc - gc)
                         : ((g == maxc) ? (2.0f + rc - bc)
                                        : (4.0f + gc - rc));
                h = hh / 6.0f;           // in (-1/6, 5/6); floor-mod 1:
                if (h < 0.0f) h += 1.0f;
            }
            bool satval = (s > 0.5f) && (v > 0.5f);
            int m = 0;
            if (satval && h >= 0.1f && h <= 0.2f) m = 1;
            else if (satval && h >= 0.55f && h <= 0.7f) m = -1;

            int x = (e == 0) ? x0 : x1;
            if (x < 39) {                 // col 39 excluded (40//3*3 == 39)
                int pan = x / 13;         // 0..2
                unsigned bit = (m > 0) ? 1u : (m < 0) ? 2u : 4u;
                my |= bit << (3 * pan);
            }
        }
    }
    return my;
}

__global__ __launch_bounds__(256)
void labelizer_fused(const float* __restrict__ in, float* __restrict__ out) {
    __shared__ float4 s4[LDS_TOT];
    __shared__ unsigned smu[4];

    const int tid = threadIdx.x, wid = tid >> 6, lane = tid & 63;
    const int img0 = blockIdx.x * IPB;
    const float4* base = (const float4*)in;
    const float* sf = (const float*)s4;
    unsigned my = 0u;

    // prologue: f0(img0) -> BUF0 (24 rows, 504 f4/ch, 6 chunks/wave)
    stageT<504, 6, 1511>(base + (size_t)img0 * IMG_F4, s4 + BUF0, wid, lane);

    for (int i = 0; i < IPB; ++i) {
        const int img = img0 + i;
        const float4* ib = base + (size_t)img * IMG_F4;

        // ---- q=0: rows 0-23 all from BUF0(f0) ----
        stageT<420, 5, 1259>(ib + 504, s4 + BUF1, wid, lane);        // f1 (rows 24-43)
        asm volatile("s_waitcnt vmcnt(5)" ::: "memory");             // f0 landed
        __builtin_amdgcn_s_barrier();
        my |= computeT<0, 2016>(nullptr, sf + BUF0 * 4, tid);
        tailcopyT<504, 20>(s4 + BUF0, s4 + TBA, tid);                // f0 rows 20-23
        asm volatile("s_waitcnt lgkmcnt(0)" ::: "memory");
        __builtin_amdgcn_s_barrier();

        // ---- q=1: TBA (f0 tail) + BUF1(f1) ----
        stageT<420, 5, 1259>(ib + 924, s4 + BUF0, wid, lane);        // f2 (rows 44-63)
        asm volatile("s_waitcnt vmcnt(5)" ::: "memory");             // f1 landed
        __builtin_amdgcn_s_barrier();
        my |= computeT<4, 1680>(sf + TBA * 4, sf + BUF1 * 4, tid);
        tailcopyT<420, 16>(s4 + BUF1, s4 + TBB, tid);                // f1 rows 40-43
        asm volatile("s_waitcnt lgkmcnt(0)" ::: "memory");
        __builtin_amdgcn_s_barrier();

        // ---- q=2: TBB (f1 tail) + BUF0(f2) ----
        stageT<420, 5, 1259>(ib + 1344, s4 + BUF1, wid, lane);       // f3 (rows 64-83)
        asm volatile("s_waitcnt vmcnt(5)" ::: "memory");             // f2 landed
        __builtin_amdgcn_s_barrier();
        my |= computeT<4, 1680>(sf + TBB * 4, sf + BUF0 * 4, tid);
        tailcopyT<420, 16>(s4 + BUF0, s4 + TBA, tid);                // f2 rows 60-63
        asm volatile("s_waitcnt lgkmcnt(0)" ::: "memory");
        __builtin_amdgcn_s_barrier();

        // ---- q=3: TBA (f2 tail) + BUF1(f3); stage next image's f0 ----
        if (i < IPB - 1) {
            stageT<504, 6, 1511>(base + (size_t)(img + 1) * IMG_F4, s4 + BUF0, wid, lane);
            asm volatile("s_waitcnt vmcnt(6)" ::: "memory");         // f3 landed, f0' flying
        } else {
            asm volatile("s_waitcnt vmcnt(0)" ::: "memory");
        }
        __builtin_amdgcn_s_barrier();
        my |= computeT<4, 1680>(sf + TBA * 4, sf + BUF1 * 4, tid);

        // image-end reduce + write (barrier doubles as q=3 trailing barrier)
        unsigned r = my;
        #pragma unroll
        for (int off = 32; off > 0; off >>= 1) r |= __shfl_xor(r, off);
        if (lane == 0) smu[wid] = r;
        asm volatile("s_waitcnt lgkmcnt(0)" ::: "memory");
        __builtin_amdgcn_s_barrier();
        if (tid < 6) {
            unsigned m4 = smu[0] | smu[1] | smu[2] | smu[3];
            int pan = (tid < 3) ? tid : tid - 3;
            unsigned w = m4 >> (3 * pan);
            bool anyY = w & 1u;
            bool anyB = (w >> 1) & 1u;
            bool anyZ = (w >> 2) & 1u;
            float val;
            if (tid < 3) val = anyY ? 1.0f : (anyZ ? 0.0f : -1.0f);   // max(panel)
            else         val = anyB ? 1.0f : (anyZ ? 0.0f : -1.0f);   // -min(panel)
            out[(size_t)img * 6 + tid] = val;
        }
        my = 0u;
    }
}

extern "C" void kernel_launch(void* const* d_in, const int* in_sizes, int n_in,
                              void* d_out, int out_size, void* d_ws, size_t ws_size,
                              hipStream_t stream) {
    const float* states = (const float*)d_in[0];
    float* out = (float*)d_out;
    int N = in_sizes[0] / (3 * CH_ELEMS);   // 4096
    labelizer_fused<<<N / IPB, 256, 0, stream>>>(states, out);
}